// Round 10
// baseline (128.987 us; speedup 1.0000x reference)
//
#include <hip/hip_runtime.h>

#define CH_EPS 1e-6f
#define NPTS 8192
#define NB 4
#define NSEG 64
#define SEGSZ (NPTS / NSEG)        // 128 refs per segment
#define CHSZ 16                    // points per argmin chunk
#define NCH (SEGSZ / CHSZ)         // 8 chunks per segment
#define QPT 8                      // queries per thread
#define QCHUNK (256 * QPT)         // 2048 queries per block
#define NQ_TOT (2 * NB * NPTS)     // 65536 queries (dir, batch, point)
#define BIGF 3.0e38f
#define CHMASK 0xFFFFFE00u         // clear low 9 bits: stuff global chunk id

// Order-preserving float->uint bijection (uint min == float min).
__device__ __forceinline__ unsigned mono(float f) {
    unsigned b = __float_as_uint(f);
    return (b & 0x80000000u) ? ~b : (b | 0x80000000u);
}
__device__ __forceinline__ unsigned mono_inv(unsigned u) {
    return (u & 0x80000000u) ? (u & 0x7FFFFFFFu) : ~u;
}

// Phase 1: per-(query, segment) chunked min scan.
// t = 0.5*|y|^2 - x.y has the same argmin as |x-y|^2 (y-dependent part).
// Hot loop: 3 FMA + 0.5 min3 per pair, scalar fp32 (pk_fma is 2-pass on
// CDNA4 -> no gain, r9). Explicit software prefetch: the next 4-ref LDS
// group is loaded into registers BEFORE the ~112-inst q-loop of the current
// group, so ds_read latency overlaps VALU. Chunk minima are folded with a
// 9-bit global chunk id stuffed into low mantissa bits; cross-segment merge
// via one device-scope atomicMin per (query, segment).
__global__ __launch_bounds__(256) void chamfer_partial(
    const float* __restrict__ xyz1, const float* __restrict__ xyz2,
    unsigned* __restrict__ part, float* __restrict__ out) {
    __shared__ float4 sY[SEGSZ];                // 2 KB

    const int tid = threadIdx.x;
    const int chq = blockIdx.x;                 // 0..3 (2048-query chunks)
    const int seg = blockIdx.y;                 // 0..NSEG-1
    const int db = blockIdx.z;                  // 0..7
    const int dir = db >> 2, b = db & 3;

    // fold output zeroing into this kernel (finalize is a later dispatch)
    if (chq == 0 && seg == 0 && db == 0 && tid < 2) out[tid] = 0.0f;

    const float* Q = dir ? xyz2 : xyz1;
    const float* R = (dir ? xyz1 : xyz2) + ((size_t)b * NPTS + seg * SEGSZ) * 3;

    // stage segment: (x, y, z, h = 0.5*|p|^2)
    if (tid < SEGSZ) {
        float a = R[3 * tid], c = R[3 * tid + 1], e = R[3 * tid + 2];
        sY[tid] = make_float4(a, c, e, 0.5f * fmaf(a, a, fmaf(c, c, e * e)));
    }

    float m0[QPT], m1[QPT], m2[QPT], bt[QPT];
    const int qi0 = chq * QCHUNK + tid;
#pragma unroll
    for (int q = 0; q < QPT; ++q) {
        const size_t off = ((size_t)b * NPTS + qi0 + q * 256) * 3;
        m0[q] = -Q[off]; m1[q] = -Q[off + 1]; m2[q] = -Q[off + 2];
        bt[q] = BIGF;
    }
    __syncthreads();

    const unsigned gc0 = seg * NCH;             // global chunk id base (uniform)

    // prime the software pipeline with group 0
    float4 a0 = sY[0], a1 = sY[1], a2 = sY[2], a3 = sY[3];

    for (int cc = 0; cc < NCH; ++cc) {
        float cm[QPT];
#pragma unroll
        for (int q = 0; q < QPT; ++q) cm[q] = BIGF;
#pragma unroll
        for (int u = 0; u < CHSZ / 4; ++u) {
            // prefetch next group (wraps to 0 at segment end -- harmless)
            const int nj = (cc * CHSZ + 4 * u + 4) & (SEGSZ - 1);
            const float4 b0 = sY[nj], b1 = sY[nj + 1],
                         b2 = sY[nj + 2], b3 = sY[nj + 3];
#pragma unroll
            for (int q = 0; q < QPT; ++q) {
                float t0 = fmaf(m0[q], a0.x, fmaf(m1[q], a0.y, fmaf(m2[q], a0.z, a0.w)));
                float t1 = fmaf(m0[q], a1.x, fmaf(m1[q], a1.y, fmaf(m2[q], a1.z, a1.w)));
                float t2 = fmaf(m0[q], a2.x, fmaf(m1[q], a2.y, fmaf(m2[q], a2.z, a2.w)));
                float t3 = fmaf(m0[q], a3.x, fmaf(m1[q], a3.y, fmaf(m2[q], a3.z, a3.w)));
                cm[q] = fminf(fminf(cm[q], t0), t1);   // -> v_min3_f32
                cm[q] = fminf(fminf(cm[q], t2), t3);   // -> v_min3_f32
            }
            a0 = b0; a1 = b1; a2 = b2; a3 = b3;
        }
        const unsigned gc = gc0 + cc;
#pragma unroll
        for (int q = 0; q < QPT; ++q) {
            // (bits & CHMASK) | gc -> single v_and_or_b32
            float kk = __uint_as_float((__float_as_uint(cm[q]) & CHMASK) | gc);
            bt[q] = fminf(bt[q], kk);
        }
    }

    const int qbase = dir * (NB * NPTS) + b * NPTS + qi0;
#pragma unroll
    for (int q = 0; q < QPT; ++q)
        atomicMin(&part[qbase + q * 256], mono(bt[q]));
}

// Phase 2: FOUR threads per query. Each rescans 4 of the winning chunk's 16
// points (3 float4 loads), quad shfl_xor butterfly with (t, idx)
// lexicographic min (exact first-argmin semantics), leader computes exact
// distance + normal-consistency, block-reduce, atomicAdd.
__global__ __launch_bounds__(256) void finalize_kernel(
    const float* __restrict__ xyz1, const float* __restrict__ xyz2,
    const float* __restrict__ nxyz1, const float* __restrict__ nxyz2,
    const unsigned* __restrict__ part, float* __restrict__ out) {
    __shared__ float red[2][4];

    const int tid = threadIdx.x;
    const int gq = blockIdx.x * 256 + tid;      // 0..262143
    const int q = gq >> 2;                      // 0..65535
    const int sub = tid & 3;                    // 4-point group within chunk
    const int dir = q >> 15;
    const int rem = q & 32767;
    const int b = rem >> 13;
    const int i = rem & 8191;

    const int c = (int)(mono_inv(part[q]) & 0x1FFu);   // global 16-pt chunk

    const float* Q   = dir ? xyz2 : xyz1;
    const float* Rf  = dir ? xyz1 : xyz2;
    const float* NQp = dir ? nxyz2 : nxyz1;
    const float* NRp = dir ? nxyz1 : nxyz2;

    const size_t qoff = ((size_t)b * NPTS + i) * 3;
    const float x0 = Q[qoff], x1 = Q[qoff + 1], x2 = Q[qoff + 2];
    const float n0 = -x0, n1 = -x1, n2 = -x2;

    // rescan this thread's 4 points (12 consecutive floats, 16B-aligned)
    const float4* Rs = (const float4*)(Rf + ((size_t)b * NPTS + c * CHSZ) * 3)
                       + 3 * sub;
    const float4 f0 = Rs[0], f1 = Rs[1], f2 = Rs[2];
    const float px[4] = {f0.x, f0.w, f1.z, f2.y};
    const float py[4] = {f0.y, f1.x, f1.w, f2.z};
    const float pz[4] = {f0.z, f1.y, f2.x, f2.w};
    float tb = BIGF;
    int bi = 0;
#pragma unroll
    for (int u = 0; u < 4; ++u) {
        float h = 0.5f * fmaf(px[u], px[u], fmaf(py[u], py[u], pz[u] * pz[u]));
        float t = fmaf(n0, px[u], fmaf(n1, py[u], fmaf(n2, pz[u], h)));
        int j = c * CHSZ + sub * 4 + u;
        if (t < tb) { tb = t; bi = j; }         // strict <, ascending j
    }
    // quad butterfly: lexicographic (t, idx) min -> exact first-argmin
#pragma unroll
    for (int off = 1; off <= 2; off <<= 1) {
        float ot = __shfl_xor(tb, off);
        int oi = __shfl_xor(bi, off);
        if (ot < tb || (ot == tb && oi < bi)) { tb = ot; bi = oi; }
    }

    float d = 0.0f, cn = 0.0f;
    if (sub == 0) {
        const size_t roff = ((size_t)b * NPTS + bi) * 3;
        const float y0 = Rf[roff], y1 = Rf[roff + 1], y2 = Rf[roff + 2];
        const float e0 = x0 - y0, e1 = x1 - y1, e2 = x2 - y2;
        d = e0 * e0 + e1 * e1 + e2 * e2;        // exact squared distance

        const float a0 = NQp[qoff], a1 = NQp[qoff + 1], a2 = NQp[qoff + 2];
        const float c0 = NRp[roff], c1 = NRp[roff + 1], c2 = NRp[roff + 2];
        float na = sqrtf(a0 * a0 + a1 * a1 + a2 * a2);
        float nc = sqrtf(c0 * c0 + c1 * c1 + c2 * c2);
        float cs = (a0 * c0 + a1 * c1 + a2 * c2) /
                   (fmaxf(na, CH_EPS) * fmaxf(nc, CH_EPS));
        cn = 1.0f - fabsf(cs);
    }

    for (int off = 32; off; off >>= 1) {
        d  += __shfl_down(d, off);
        cn += __shfl_down(cn, off);
    }
    const int lane = tid & 63, wv = tid >> 6;
    if (lane == 0) { red[0][wv] = d; red[1][wv] = cn; }
    __syncthreads();
    if (tid == 0) {
        float sd = red[0][0] + red[0][1] + red[0][2] + red[0][3];
        float sc = red[1][0] + red[1][1] + red[1][2] + red[1][3];
        const float inv = 1.0f / (float)(NB * NPTS);   // 1/32768
        atomicAdd(out + 0, sd * inv);
        atomicAdd(out + 1, sc * inv);
    }
}

extern "C" void kernel_launch(void* const* d_in, const int* in_sizes, int n_in,
                              void* d_out, int out_size, void* d_ws, size_t ws_size,
                              hipStream_t stream) {
    const float* xyz1  = (const float*)d_in[0];
    const float* xyz2  = (const float*)d_in[1];
    const float* nxyz1 = (const float*)d_in[2];
    const float* nxyz2 = (const float*)d_in[3];
    float* out = (float*)d_out;
    unsigned* part = (unsigned*)d_ws;           // 65536 * 4 B = 256 KB

    // init keys to +inf (all-ones = uint max)
    hipMemsetAsync(part, 0xFF, (size_t)NQ_TOT * sizeof(unsigned), stream);
    chamfer_partial<<<dim3(NPTS / QCHUNK, NSEG, 2 * NB), dim3(256), 0, stream>>>(
        xyz1, xyz2, part, out);
    finalize_kernel<<<dim3(4 * NQ_TOT / 256, 1, 1), dim3(256), 0, stream>>>(
        xyz1, xyz2, nxyz1, nxyz2, part, out);
}

// Round 11
// 124.834 us; speedup vs baseline: 1.0333x; 1.0333x over previous
//
#include <hip/hip_runtime.h>

#define CH_EPS 1e-6f
#define NPTS 8192
#define NB 4
#define NSEG 8
#define SEGSZ (NPTS / NSEG)        // 1024 refs per segment
#define TILE 16                    // refs per MFMA tile == argmin chunk
#define NTILE (SEGSZ / TILE)       // 64 ref tiles per segment
#define NQT 8                      // query tiles per wave
#define QPW (16 * NQT)             // 128 queries per wave
#define QPB (4 * QPW)              // 512 queries per block
#define NQ_TOT (2 * NB * NPTS)     // 65536 queries
#define BIGF 3.0e38f
#define CHMASK 0xFFFFFE00u         // clear low 9 bits: stuff global tile id

typedef _Float16 half8 __attribute__((ext_vector_type(8)));
typedef float floatx4 __attribute__((ext_vector_type(4)));

// Order-preserving float->uint bijection (uint min == float min).
__device__ __forceinline__ unsigned mono(float f) {
    unsigned b = __float_as_uint(f);
    return (b & 0x80000000u) ? ~b : (b | 0x80000000u);
}
__device__ __forceinline__ unsigned mono_inv(unsigned u) {
    return (u & 0x80000000u) ? (u & 0x7FFFFFFFu) : ~u;
}

// Phase 1, MFMA engine. t = 0.5*|y|^2 - x.y as a 4D dot product:
// A (M=16 refs) rows = [y0 y1 y2 h 0..], B (N=16 queries) cols =
// [-x0 -x1 -x2 1 0..], one v_mfma_f32_16x16x32_f16 = 256 pair-t's.
// D layout (m89): col=lane&15 (query), row=quad*4+reg (ref) -> per-lane
// tree-min over 4 refs, stuff 9-bit global tile id, fold into running best;
// cross-quad shfl fold at the end + one atomicMin per (query, segment).
// f16 noise (~3e-3 on t) only affects WHICH 16-pt chunk wins; finalize
// re-scans the winning chunk in exact fp32.
__global__ __launch_bounds__(256) void chamfer_partial(
    const float* __restrict__ xyz1, const float* __restrict__ xyz2,
    unsigned* __restrict__ part, float* __restrict__ out) {
    __shared__ half8 sA[SEGSZ + 1];             // packed ref frags + zero slot

    const int tid = threadIdx.x;
    const int chq = blockIdx.x;                 // 0..15 (512-query chunks)
    const int seg = blockIdx.y;                 // 0..NSEG-1
    const int db = blockIdx.z;                  // 0..7
    const int dir = db >> 2, b = db & 3;

    // fold output zeroing into this kernel (finalize is a later dispatch)
    if (chq == 0 && seg == 0 && db == 0 && tid < 2) out[tid] = 0.0f;

    const float* Q = dir ? xyz2 : xyz1;
    const float* R = (dir ? xyz1 : xyz2) + ((size_t)b * NPTS + seg * SEGSZ) * 3;

    // pack refs: (y0, y1, y2, h, 0,0,0,0) as f16x8 (one A-frag row per ref)
    for (int k = tid; k < SEGSZ; k += 256) {
        float a = R[3 * k], c = R[3 * k + 1], e = R[3 * k + 2];
        float h = 0.5f * fmaf(a, a, fmaf(c, c, e * e));
        half8 v = {(_Float16)a, (_Float16)c, (_Float16)e, (_Float16)h,
                   (_Float16)0, (_Float16)0, (_Float16)0, (_Float16)0};
        sA[k] = v;
    }
    if (tid == 0) {
        half8 z = {(_Float16)0, (_Float16)0, (_Float16)0, (_Float16)0,
                   (_Float16)0, (_Float16)0, (_Float16)0, (_Float16)0};
        sA[SEGSZ] = z;                          // zero frag for quads 1..3
    }

    const int wave = tid >> 6, lane = tid & 63;
    const int m = lane & 15;
    const bool q0 = lane < 16;                  // quad 0 carries k=0..7 data
    const int qbase = chq * QPB + wave * QPW;   // query base within cloud

    // B-frags: query n = qbase + qt*16 + (lane&15); quad0 = [-x,-y,-z,1,0..]
    half8 bfrag[NQT];
    float best[NQT];
#pragma unroll
    for (int qt = 0; qt < NQT; ++qt) {
        half8 v = {(_Float16)0, (_Float16)0, (_Float16)0, (_Float16)0,
                   (_Float16)0, (_Float16)0, (_Float16)0, (_Float16)0};
        if (q0) {
            const size_t off = ((size_t)b * NPTS + qbase + qt * 16 + m) * 3;
            v[0] = (_Float16)(-Q[off]);
            v[1] = (_Float16)(-Q[off + 1]);
            v[2] = (_Float16)(-Q[off + 2]);
            v[3] = (_Float16)1.0f;
        }
        bfrag[qt] = v;
        best[qt] = BIGF;
    }
    __syncthreads();

    const unsigned gc0 = seg * NTILE;           // global tile id base (uniform)
    const floatx4 zacc = {0.0f, 0.0f, 0.0f, 0.0f};

    for (int rt = 0; rt < NTILE; ++rt) {
        const half8 af = sA[q0 ? (rt * 16 + m) : SEGSZ];
        const unsigned gc = gc0 + rt;
#pragma unroll
        for (int qt = 0; qt < NQT; ++qt) {
            floatx4 d = __builtin_amdgcn_mfma_f32_16x16x32_f16(
                af, bfrag[qt], zacc, 0, 0, 0);
            float mn = fminf(fminf(d[0], d[1]), fminf(d[2], d[3]));
            float key = __uint_as_float((__float_as_uint(mn) & CHMASK) | gc);
            best[qt] = fminf(best[qt], key);
        }
    }

    // cross-quad fold (quads cover disjoint refs) + one atomic per query
    const int qg = dir * (NB * NPTS) + b * NPTS + qbase;
#pragma unroll
    for (int qt = 0; qt < NQT; ++qt) {
        float v = best[qt];
        v = fminf(v, __shfl_xor(v, 16));
        v = fminf(v, __shfl_xor(v, 32));
        if (q0) atomicMin(&part[qg + qt * 16 + m], mono(v));
    }
}

// Phase 2 (r9 structure): decode winning 16-pt chunk, re-scan exactly via
// float4 loads, distance + normal-consistency, block-reduce, atomicAdd.
__global__ __launch_bounds__(256) void finalize_kernel(
    const float* __restrict__ xyz1, const float* __restrict__ xyz2,
    const float* __restrict__ nxyz1, const float* __restrict__ nxyz2,
    const unsigned* __restrict__ part, float* __restrict__ out) {
    __shared__ float red[2][4];

    const int tid = threadIdx.x;
    const int q = blockIdx.x * 256 + tid;       // 0..65535
    const int dir = q >> 15;
    const int rem = q & 32767;
    const int b = rem >> 13;
    const int i = rem & 8191;

    const int c = (int)(mono_inv(part[q]) & 0x1FFu);   // global 16-pt chunk

    const float* Q   = dir ? xyz2 : xyz1;
    const float* Rf  = dir ? xyz1 : xyz2;
    const float* NQp = dir ? nxyz2 : nxyz1;
    const float* NRp = dir ? nxyz1 : nxyz2;

    const size_t qoff = ((size_t)b * NPTS + i) * 3;
    const float x0 = Q[qoff], x1 = Q[qoff + 1], x2 = Q[qoff + 2];
    const float n0 = -x0, n1 = -x1, n2 = -x2;

    // re-scan winning chunk (16 pts = 12 float4 loads; base 192B-aligned)
    const float4* Rs = (const float4*)(Rf + ((size_t)b * NPTS + c * TILE) * 3);
    float btr = BIGF;
    int bj = 0;
#pragma unroll
    for (int g = 0; g < 4; ++g) {               // 4 groups of 4 points
        const float4 f0 = Rs[3 * g];
        const float4 f1 = Rs[3 * g + 1];
        const float4 f2 = Rs[3 * g + 2];
        const float px[4] = {f0.x, f0.w, f1.z, f2.y};
        const float py[4] = {f0.y, f1.x, f1.w, f2.z};
        const float pz[4] = {f0.z, f1.y, f2.x, f2.w};
#pragma unroll
        for (int u = 0; u < 4; ++u) {
            float h = 0.5f * fmaf(px[u], px[u], fmaf(py[u], py[u], pz[u] * pz[u]));
            float t = fmaf(n0, px[u], fmaf(n1, py[u], fmaf(n2, pz[u], h)));
            int j = 4 * g + u;
            if (t < btr) { btr = t; bj = j; }   // strict <, ascending j: exact
        }
    }
    const int bi = c * TILE + bj;

    const size_t roff = ((size_t)b * NPTS + bi) * 3;
    const float y0 = Rf[roff], y1 = Rf[roff + 1], y2 = Rf[roff + 2];
    const float e0 = x0 - y0, e1 = x1 - y1, e2 = x2 - y2;
    float d = e0 * e0 + e1 * e1 + e2 * e2;      // exact squared distance

    const float a0 = NQp[qoff], a1 = NQp[qoff + 1], a2 = NQp[qoff + 2];
    const float c0 = NRp[roff], c1 = NRp[roff + 1], c2 = NRp[roff + 2];
    float na = sqrtf(a0 * a0 + a1 * a1 + a2 * a2);
    float nc = sqrtf(c0 * c0 + c1 * c1 + c2 * c2);
    float cs = (a0 * c0 + a1 * c1 + a2 * c2) /
               (fmaxf(na, CH_EPS) * fmaxf(nc, CH_EPS));
    float cn = 1.0f - fabsf(cs);

    for (int off = 32; off; off >>= 1) {
        d  += __shfl_down(d, off);
        cn += __shfl_down(cn, off);
    }
    const int lane = tid & 63, wv = tid >> 6;
    if (lane == 0) { red[0][wv] = d; red[1][wv] = cn; }
    __syncthreads();
    if (tid == 0) {
        float sd = red[0][0] + red[0][1] + red[0][2] + red[0][3];
        float sc = red[1][0] + red[1][1] + red[1][2] + red[1][3];
        const float inv = 1.0f / (float)(NB * NPTS);   // 1/32768
        atomicAdd(out + 0, sd * inv);
        atomicAdd(out + 1, sc * inv);
    }
}

extern "C" void kernel_launch(void* const* d_in, const int* in_sizes, int n_in,
                              void* d_out, int out_size, void* d_ws, size_t ws_size,
                              hipStream_t stream) {
    const float* xyz1  = (const float*)d_in[0];
    const float* xyz2  = (const float*)d_in[1];
    const float* nxyz1 = (const float*)d_in[2];
    const float* nxyz2 = (const float*)d_in[3];
    float* out = (float*)d_out;
    unsigned* part = (unsigned*)d_ws;           // 65536 * 4 B = 256 KB

    // init keys to +inf (all-ones = uint max)
    hipMemsetAsync(part, 0xFF, (size_t)NQ_TOT * sizeof(unsigned), stream);
    chamfer_partial<<<dim3(NPTS / QPB, NSEG, 2 * NB), dim3(256), 0, stream>>>(
        xyz1, xyz2, part, out);
    finalize_kernel<<<dim3(NQ_TOT / 256), dim3(256), 0, stream>>>(
        xyz1, xyz2, nxyz1, nxyz2, part, out);
}

// Round 12
// 105.951 us; speedup vs baseline: 1.2174x; 1.1782x over previous
//
#include <hip/hip_runtime.h>

#define CH_EPS 1e-6f
#define NPTS 8192
#define NB 4
#define NSEG 8
#define SEGSZ (NPTS / NSEG)        // 1024 refs per segment
#define TILE 32                    // refs per MFMA tile (two 16-pt chunks)
#define NTILE (SEGSZ / TILE)       // 32 ref tiles per segment
#define CHSZ 16                    // argmin chunk (finalize rescan unit)
#define NQT 4                      // query tiles (32 q) per wave
#define QPW (32 * NQT)             // 128 queries per wave
#define QPB (4 * QPW)              // 512 queries per block
#define NQ_TOT (2 * NB * NPTS)     // 65536 queries
#define BIGF 3.0e38f
#define CHMASK 0xFFFFFE00u         // clear low 9 bits: stuff global chunk id

typedef _Float16 half8 __attribute__((ext_vector_type(8)));
typedef float floatx16 __attribute__((ext_vector_type(16)));

// Order-preserving float->uint bijection (uint min == float min).
__device__ __forceinline__ unsigned mono(float f) {
    unsigned b = __float_as_uint(f);
    return (b & 0x80000000u) ? ~b : (b | 0x80000000u);
}
__device__ __forceinline__ unsigned mono_inv(unsigned u) {
    return (u & 0x80000000u) ? (u & 0x7FFFFFFFu) : ~u;
}

// Phase 1, 32x32x16 f16 MFMA engine. t = 0.5*|y|^2 - x.y as a 4D dot:
// A rows (M=32 refs) = [y0 y1 y2 h 0..], B cols (N=32 queries) =
// [-x0 -x1 -x2 1 0..]; one MFMA = 1024 pair-t's (~8 cyc). D layout
// (m74/m101): col=lane&31 (query), row=(reg&3)+8*(reg>>2)+4*(lane>>5) ->
// regs 0-7 = rows 0-15, regs 8-15 = rows 16-31: two 8-value min trees give
// the two 16-pt chunk minima directly. Stuff 9-bit global chunk id into low
// mantissa; cross-half shfl fold at the end + one atomicMin per query.
// f16 noise only affects WHICH chunk wins; finalize rescans in exact fp32.
__global__ __launch_bounds__(256) void chamfer_partial(
    const float* __restrict__ xyz1, const float* __restrict__ xyz2,
    unsigned* __restrict__ part, float* __restrict__ out) {
    __shared__ half8 sA[SEGSZ + 1];             // packed ref frags + zero slot

    const int tid = threadIdx.x;
    const int chq = blockIdx.x;                 // 0..15 (512-query chunks)
    const int seg = blockIdx.y;                 // 0..NSEG-1
    const int db = blockIdx.z;                  // 0..7
    const int dir = db >> 2, b = db & 3;

    // fold output zeroing into this kernel (finalize is a later dispatch)
    if (chq == 0 && seg == 0 && db == 0 && tid < 2) out[tid] = 0.0f;

    const float* Q = dir ? xyz2 : xyz1;
    const float* R = (dir ? xyz1 : xyz2) + ((size_t)b * NPTS + seg * SEGSZ) * 3;

    // pack refs: (y0, y1, y2, h, 0,0,0,0) as f16x8 (one A-frag row per ref)
    for (int k = tid; k < SEGSZ; k += 256) {
        float a = R[3 * k], c = R[3 * k + 1], e = R[3 * k + 2];
        float h = 0.5f * fmaf(a, a, fmaf(c, c, e * e));
        half8 v = {(_Float16)a, (_Float16)c, (_Float16)e, (_Float16)h,
                   (_Float16)0, (_Float16)0, (_Float16)0, (_Float16)0};
        sA[k] = v;
    }
    if (tid == 0) {
        half8 z = {(_Float16)0, (_Float16)0, (_Float16)0, (_Float16)0,
                   (_Float16)0, (_Float16)0, (_Float16)0, (_Float16)0};
        sA[SEGSZ] = z;                          // zero frag for k=8..15 half
    }

    const int wave = tid >> 6, lane = tid & 63;
    const int n = lane & 31;
    const bool lohalf = lane < 32;              // k=0..7 carriers
    const int qbase = chq * QPB + wave * QPW;

    // B-frags: query col n; low half = [-x,-y,-z,1,0..], high half = zeros
    half8 bfrag[NQT];
    float best[NQT];
#pragma unroll
    for (int qt = 0; qt < NQT; ++qt) {
        half8 v = {(_Float16)0, (_Float16)0, (_Float16)0, (_Float16)0,
                   (_Float16)0, (_Float16)0, (_Float16)0, (_Float16)0};
        if (lohalf) {
            const size_t off = ((size_t)b * NPTS + qbase + qt * 32 + n) * 3;
            v[0] = (_Float16)(-Q[off]);
            v[1] = (_Float16)(-Q[off + 1]);
            v[2] = (_Float16)(-Q[off + 2]);
            v[3] = (_Float16)1.0f;
        }
        bfrag[qt] = v;
        best[qt] = BIGF;
    }
    __syncthreads();

    const floatx16 zacc = {0};
    const unsigned gt0 = seg * NTILE;           // global tile id base (uniform)

    for (int rt = 0; rt < NTILE; ++rt) {
        // A-frag: low half reads ref row (tile*32 + n), high half reads zeros
        const half8 af = sA[lohalf ? (rt * TILE + n) : SEGSZ];
        const unsigned gcl = (gt0 + rt) * 2;    // low 16-pt chunk id

        floatx16 d[NQT];
#pragma unroll
        for (int qt = 0; qt < NQT; ++qt)        // 4 back-to-back MFMAs
            d[qt] = __builtin_amdgcn_mfma_f32_32x32x16_f16(
                af, bfrag[qt], zacc, 0, 0, 0);

#pragma unroll
        for (int qt = 0; qt < NQT; ++qt) {
            // regs 0-7 = rows 0-15 (low chunk), regs 8-15 = rows 16-31 (high)
            float lo = fminf(fminf(fminf(d[qt][0], d[qt][1]), fminf(d[qt][2], d[qt][3])),
                             fminf(fminf(d[qt][4], d[qt][5]), fminf(d[qt][6], d[qt][7])));
            float hi = fminf(fminf(fminf(d[qt][8], d[qt][9]), fminf(d[qt][10], d[qt][11])),
                             fminf(fminf(d[qt][12], d[qt][13]), fminf(d[qt][14], d[qt][15])));
            float kl = __uint_as_float((__float_as_uint(lo) & CHMASK) | gcl);
            float kh = __uint_as_float((__float_as_uint(hi) & CHMASK) | (gcl + 1));
            best[qt] = fminf(best[qt], fminf(kl, kh));
        }
    }

    // cross-half fold (halves cover disjoint refs) + one atomic per query
    const int qg = dir * (NB * NPTS) + b * NPTS + qbase;
#pragma unroll
    for (int qt = 0; qt < NQT; ++qt) {
        float v = best[qt];
        v = fminf(v, __shfl_xor(v, 32));
        if (lohalf) atomicMin(&part[qg + qt * 32 + n], mono(v));
    }
}

// Phase 2 (r9 structure): decode winning 16-pt chunk, re-scan exactly via
// float4 loads, distance + normal-consistency, block-reduce, atomicAdd.
__global__ __launch_bounds__(256) void finalize_kernel(
    const float* __restrict__ xyz1, const float* __restrict__ xyz2,
    const float* __restrict__ nxyz1, const float* __restrict__ nxyz2,
    const unsigned* __restrict__ part, float* __restrict__ out) {
    __shared__ float red[2][4];

    const int tid = threadIdx.x;
    const int q = blockIdx.x * 256 + tid;       // 0..65535
    const int dir = q >> 15;
    const int rem = q & 32767;
    const int b = rem >> 13;
    const int i = rem & 8191;

    const int c = (int)(mono_inv(part[q]) & 0x1FFu);   // global 16-pt chunk

    const float* Q   = dir ? xyz2 : xyz1;
    const float* Rf  = dir ? xyz1 : xyz2;
    const float* NQp = dir ? nxyz2 : nxyz1;
    const float* NRp = dir ? nxyz1 : nxyz2;

    const size_t qoff = ((size_t)b * NPTS + i) * 3;
    const float x0 = Q[qoff], x1 = Q[qoff + 1], x2 = Q[qoff + 2];
    const float n0 = -x0, n1 = -x1, n2 = -x2;

    // re-scan winning chunk (16 pts = 12 float4 loads; base 192B-aligned)
    const float4* Rs = (const float4*)(Rf + ((size_t)b * NPTS + c * CHSZ) * 3);
    float btr = BIGF;
    int bj = 0;
#pragma unroll
    for (int g = 0; g < 4; ++g) {               // 4 groups of 4 points
        const float4 f0 = Rs[3 * g];
        const float4 f1 = Rs[3 * g + 1];
        const float4 f2 = Rs[3 * g + 2];
        const float px[4] = {f0.x, f0.w, f1.z, f2.y};
        const float py[4] = {f0.y, f1.x, f1.w, f2.z};
        const float pz[4] = {f0.z, f1.y, f2.x, f2.w};
#pragma unroll
        for (int u = 0; u < 4; ++u) {
            float h = 0.5f * fmaf(px[u], px[u], fmaf(py[u], py[u], pz[u] * pz[u]));
            float t = fmaf(n0, px[u], fmaf(n1, py[u], fmaf(n2, pz[u], h)));
            int j = 4 * g + u;
            if (t < btr) { btr = t; bj = j; }   // strict <, ascending j: exact
        }
    }
    const int bi = c * CHSZ + bj;

    const size_t roff = ((size_t)b * NPTS + bi) * 3;
    const float y0 = Rf[roff], y1 = Rf[roff + 1], y2 = Rf[roff + 2];
    const float e0 = x0 - y0, e1 = x1 - y1, e2 = x2 - y2;
    float d = e0 * e0 + e1 * e1 + e2 * e2;      // exact squared distance

    const float a0 = NQp[qoff], a1 = NQp[qoff + 1], a2 = NQp[qoff + 2];
    const float c0 = NRp[roff], c1 = NRp[roff + 1], c2 = NRp[roff + 2];
    float na = sqrtf(a0 * a0 + a1 * a1 + a2 * a2);
    float nc = sqrtf(c0 * c0 + c1 * c1 + c2 * c2);
    float cs = (a0 * c0 + a1 * c1 + a2 * c2) /
               (fmaxf(na, CH_EPS) * fmaxf(nc, CH_EPS));
    float cn = 1.0f - fabsf(cs);

    for (int off = 32; off; off >>= 1) {
        d  += __shfl_down(d, off);
        cn += __shfl_down(cn, off);
    }
    const int lane = tid & 63, wv = tid >> 6;
    if (lane == 0) { red[0][wv] = d; red[1][wv] = cn; }
    __syncthreads();
    if (tid == 0) {
        float sd = red[0][0] + red[0][1] + red[0][2] + red[0][3];
        float sc = red[1][0] + red[1][1] + red[1][2] + red[1][3];
        const float inv = 1.0f / (float)(NB * NPTS);   // 1/32768
        atomicAdd(out + 0, sd * inv);
        atomicAdd(out + 1, sc * inv);
    }
}

extern "C" void kernel_launch(void* const* d_in, const int* in_sizes, int n_in,
                              void* d_out, int out_size, void* d_ws, size_t ws_size,
                              hipStream_t stream) {
    const float* xyz1  = (const float*)d_in[0];
    const float* xyz2  = (const float*)d_in[1];
    const float* nxyz1 = (const float*)d_in[2];
    const float* nxyz2 = (const float*)d_in[3];
    float* out = (float*)d_out;
    unsigned* part = (unsigned*)d_ws;           // 65536 * 4 B = 256 KB

    // init keys to +inf (all-ones = uint max)
    hipMemsetAsync(part, 0xFF, (size_t)NQ_TOT * sizeof(unsigned), stream);
    chamfer_partial<<<dim3(NPTS / QPB, NSEG, 2 * NB), dim3(256), 0, stream>>>(
        xyz1, xyz2, part, out);
    finalize_kernel<<<dim3(NQ_TOT / 256), dim3(256), 0, stream>>>(
        xyz1, xyz2, nxyz1, nxyz2, part, out);
}

// Round 13
// 104.113 us; speedup vs baseline: 1.2389x; 1.0177x over previous
//
#include <hip/hip_runtime.h>

#define CH_EPS 1e-6f
#define NPTS 8192
#define NB 4
#define NSEG 16
#define SEGSZ (NPTS / NSEG)        // 512 refs per segment
#define TILE 32                    // refs per MFMA tile == argmin chunk
#define NTILE (SEGSZ / TILE)       // 16 ref tiles per segment
#define CHSZ 32                    // finalize rescan unit (= TILE)
#define NQT 4                      // query tiles (32 q) per wave
#define QPW (32 * NQT)             // 128 queries per wave
#define QPB (4 * QPW)              // 512 queries per block
#define NQ_TOT (2 * NB * NPTS)     // 65536 queries
#define BIGF 3.0e38f
#define CHMASK 0xFFFFFF00u         // clear low 8 bits: stuff global chunk id

typedef _Float16 half8 __attribute__((ext_vector_type(8)));
typedef float floatx16 __attribute__((ext_vector_type(16)));

// Phase 1, 32x32x16 f16 MFMA engine. t = 0.5*|y|^2 - x.y as a 4D dot:
// A rows (M=32 refs) = [y0 y1 y2 h 0..], B cols (N=32 queries) =
// [-x0 -x1 -x2 1 0..]; one MFMA = 1024 pair-t's. D is consumed IMMEDIATELY
// (single transient floatx16) so the compiler keeps zacc pinned and does no
// per-MFMA accumulator re-zero / AGPR round-trip (r12's 84-inst/MFMA tax).
// Whole 32-ref tile = one argmin chunk: 16-reg min tree -> stuff 8-bit
// global chunk id into low mantissa -> fold into per-query best. Cross-half
// shfl fold at the end; plain keyed STORES to part[seg][q] (no atomics, no
// memset dispatch). f16 noise only affects WHICH chunk wins; finalize
// re-scans the winning chunk in exact fp32.
__global__ __launch_bounds__(256) void chamfer_partial(
    const float* __restrict__ xyz1, const float* __restrict__ xyz2,
    float* __restrict__ part, float* __restrict__ out) {
    __shared__ half8 sA[SEGSZ + 1];             // packed ref frags + zero slot

    const int tid = threadIdx.x;
    const int chq = blockIdx.x;                 // 0..15 (512-query chunks)
    const int seg = blockIdx.y;                 // 0..NSEG-1
    const int db = blockIdx.z;                  // 0..7
    const int dir = db >> 2, b = db & 3;

    // fold output zeroing into this kernel (finalize is a later dispatch)
    if (chq == 0 && seg == 0 && db == 0 && tid < 2) out[tid] = 0.0f;

    const float* Q = dir ? xyz2 : xyz1;
    const float* R = (dir ? xyz1 : xyz2) + ((size_t)b * NPTS + seg * SEGSZ) * 3;

    // pack refs: (y0, y1, y2, h, 0,0,0,0) as f16x8 (one A-frag row per ref)
    for (int k = tid; k < SEGSZ; k += 256) {
        float a = R[3 * k], c = R[3 * k + 1], e = R[3 * k + 2];
        float h = 0.5f * fmaf(a, a, fmaf(c, c, e * e));
        half8 v = {(_Float16)a, (_Float16)c, (_Float16)e, (_Float16)h,
                   (_Float16)0, (_Float16)0, (_Float16)0, (_Float16)0};
        sA[k] = v;
    }
    if (tid == 0) {
        half8 z = {(_Float16)0, (_Float16)0, (_Float16)0, (_Float16)0,
                   (_Float16)0, (_Float16)0, (_Float16)0, (_Float16)0};
        sA[SEGSZ] = z;                          // zero frag for k=8..15 half
    }

    const int wave = tid >> 6, lane = tid & 63;
    const int n = lane & 31;
    const bool lohalf = lane < 32;              // k=0..7 carriers
    const int qbase = chq * QPB + wave * QPW;

    // B-frags: query col n; low half = [-x,-y,-z,1,0..], high half = zeros
    half8 bfrag[NQT];
    float best[NQT];
#pragma unroll
    for (int qt = 0; qt < NQT; ++qt) {
        half8 v = {(_Float16)0, (_Float16)0, (_Float16)0, (_Float16)0,
                   (_Float16)0, (_Float16)0, (_Float16)0, (_Float16)0};
        if (lohalf) {
            const size_t off = ((size_t)b * NPTS + qbase + qt * 32 + n) * 3;
            v[0] = (_Float16)(-Q[off]);
            v[1] = (_Float16)(-Q[off + 1]);
            v[2] = (_Float16)(-Q[off + 2]);
            v[3] = (_Float16)1.0f;
        }
        bfrag[qt] = v;
        best[qt] = BIGF;
    }
    __syncthreads();

    const floatx16 zacc = {0};
    const unsigned gc0 = seg * NTILE;           // global chunk id base (uniform)

    for (int rt = 0; rt < NTILE; ++rt) {
        // A-frag: low half reads ref row (tile*32 + n), high half reads zeros
        const half8 af = sA[lohalf ? (rt * TILE + n) : SEGSZ];
        const unsigned gc = gc0 + rt;
#pragma unroll
        for (int qt = 0; qt < NQT; ++qt) {
            floatx16 d = __builtin_amdgcn_mfma_f32_32x32x16_f16(
                af, bfrag[qt], zacc, 0, 0, 0);
            // balanced 16-value min tree (fuses to v_min3_f32 chains)
            float m0 = fminf(fminf(d[0], d[1]), fminf(d[2], d[3]));
            float m1 = fminf(fminf(d[4], d[5]), fminf(d[6], d[7]));
            float m2 = fminf(fminf(d[8], d[9]), fminf(d[10], d[11]));
            float m3 = fminf(fminf(d[12], d[13]), fminf(d[14], d[15]));
            float mn = fminf(fminf(m0, m1), fminf(m2, m3));
            // (bits & CHMASK) | gc -> v_and_or_b32
            float key = __uint_as_float((__float_as_uint(mn) & CHMASK) | gc);
            best[qt] = fminf(best[qt], key);
        }
    }

    // cross-half fold (halves cover disjoint D rows) + plain keyed store
    const int qg = dir * (NB * NPTS) + b * NPTS + qbase;
#pragma unroll
    for (int qt = 0; qt < NQT; ++qt) {
        float v = best[qt];
        v = fminf(v, __shfl_xor(v, 32));
        if (lohalf) part[(size_t)seg * NQ_TOT + qg + qt * 32 + n] = v;
    }
}

// Phase 2: merge NSEG keyed segment minima (pure fminf, coalesced), decode
// winning 32-pt chunk, re-scan exactly via float4 loads, distance +
// normal-consistency, block-reduce, atomicAdd.
__global__ __launch_bounds__(256) void finalize_kernel(
    const float* __restrict__ xyz1, const float* __restrict__ xyz2,
    const float* __restrict__ nxyz1, const float* __restrict__ nxyz2,
    const float* __restrict__ part, float* __restrict__ out) {
    __shared__ float red[2][4];

    const int tid = threadIdx.x;
    const int q = blockIdx.x * 256 + tid;       // 0..65535
    const int dir = q >> 15;
    const int rem = q & 32767;
    const int b = rem >> 13;
    const int i = rem & 8191;

    float bt = part[q];
#pragma unroll
    for (int s = 1; s < NSEG; ++s) bt = fminf(bt, part[(size_t)s * NQ_TOT + q]);
    const int c = (int)(__float_as_uint(bt) & 0xFFu);  // global 32-pt chunk

    const float* Q   = dir ? xyz2 : xyz1;
    const float* Rf  = dir ? xyz1 : xyz2;
    const float* NQp = dir ? nxyz2 : nxyz1;
    const float* NRp = dir ? nxyz1 : nxyz2;

    const size_t qoff = ((size_t)b * NPTS + i) * 3;
    const float x0 = Q[qoff], x1 = Q[qoff + 1], x2 = Q[qoff + 2];
    const float n0 = -x0, n1 = -x1, n2 = -x2;

    // re-scan winning chunk (32 pts = 24 float4 loads; base 384B-aligned)
    const float4* Rs = (const float4*)(Rf + ((size_t)b * NPTS + c * CHSZ) * 3);
    float btr = BIGF;
    int bj = 0;
#pragma unroll
    for (int g = 0; g < 8; ++g) {               // 8 groups of 4 points
        const float4 f0 = Rs[3 * g];
        const float4 f1 = Rs[3 * g + 1];
        const float4 f2 = Rs[3 * g + 2];
        const float px[4] = {f0.x, f0.w, f1.z, f2.y};
        const float py[4] = {f0.y, f1.x, f1.w, f2.z};
        const float pz[4] = {f0.z, f1.y, f2.x, f2.w};
#pragma unroll
        for (int u = 0; u < 4; ++u) {
            float h = 0.5f * fmaf(px[u], px[u], fmaf(py[u], py[u], pz[u] * pz[u]));
            float t = fmaf(n0, px[u], fmaf(n1, py[u], fmaf(n2, pz[u], h)));
            int j = 4 * g + u;
            if (t < btr) { btr = t; bj = j; }   // strict <, ascending j: exact
        }
    }
    const int bi = c * CHSZ + bj;

    const size_t roff = ((size_t)b * NPTS + bi) * 3;
    const float y0 = Rf[roff], y1 = Rf[roff + 1], y2 = Rf[roff + 2];
    const float e0 = x0 - y0, e1 = x1 - y1, e2 = x2 - y2;
    float d = e0 * e0 + e1 * e1 + e2 * e2;      // exact squared distance

    const float a0 = NQp[qoff], a1 = NQp[qoff + 1], a2 = NQp[qoff + 2];
    const float c0 = NRp[roff], c1 = NRp[roff + 1], c2 = NRp[roff + 2];
    float na = sqrtf(a0 * a0 + a1 * a1 + a2 * a2);
    float nc = sqrtf(c0 * c0 + c1 * c1 + c2 * c2);
    float cs = (a0 * c0 + a1 * c1 + a2 * c2) /
               (fmaxf(na, CH_EPS) * fmaxf(nc, CH_EPS));
    float cn = 1.0f - fabsf(cs);

    for (int off = 32; off; off >>= 1) {
        d  += __shfl_down(d, off);
        cn += __shfl_down(cn, off);
    }
    const int lane = tid & 63, wv = tid >> 6;
    if (lane == 0) { red[0][wv] = d; red[1][wv] = cn; }
    __syncthreads();
    if (tid == 0) {
        float sd = red[0][0] + red[0][1] + red[0][2] + red[0][3];
        float sc = red[1][0] + red[1][1] + red[1][2] + red[1][3];
        const float inv = 1.0f / (float)(NB * NPTS);   // 1/32768
        atomicAdd(out + 0, sd * inv);
        atomicAdd(out + 1, sc * inv);
    }
}

extern "C" void kernel_launch(void* const* d_in, const int* in_sizes, int n_in,
                              void* d_out, int out_size, void* d_ws, size_t ws_size,
                              hipStream_t stream) {
    const float* xyz1  = (const float*)d_in[0];
    const float* xyz2  = (const float*)d_in[1];
    const float* nxyz1 = (const float*)d_in[2];
    const float* nxyz2 = (const float*)d_in[3];
    float* out = (float*)d_out;
    float* part = (float*)d_ws;                 // NSEG * 65536 * 4 B = 4 MB

    chamfer_partial<<<dim3(NPTS / QPB, NSEG, 2 * NB), dim3(256), 0, stream>>>(
        xyz1, xyz2, part, out);
    finalize_kernel<<<dim3(NQ_TOT / 256), dim3(256), 0, stream>>>(
        xyz1, xyz2, nxyz1, nxyz2, part, out);
}

// Round 15
// 93.309 us; speedup vs baseline: 1.3824x; 1.1158x over previous
//
#include <hip/hip_runtime.h>

#define CH_EPS 1e-6f
#define NPTS 8192
#define NB 4
#define NSEG 16
#define SEGSZ (NPTS / NSEG)        // 512 refs per segment
#define TILE 32                    // refs per MFMA tile == argmin chunk
#define NTILE (SEGSZ / TILE)       // 16 ref tiles per segment
#define CHSZ 32                    // finalize rescan unit (= TILE)
#define NQT 4                      // query tiles (32 q) per wave
#define QPW (32 * NQT)             // 128 queries per wave
#define QPB (4 * QPW)              // 512 queries per block
#define NQ_TOT (2 * NB * NPTS)     // 65536 queries
#define BIGF 3.0e38f
#define CHMASK 0xFFFFFF00u         // clear low 8 bits: stuff global chunk id

typedef _Float16 half8 __attribute__((ext_vector_type(8)));
typedef float floatx16 __attribute__((ext_vector_type(16)));

// Phase 1, 32x32x16 f16 MFMA engine. t = 0.5*|y|^2 - x.y as a 4D dot:
// A rows (M=32 refs) = [y0 y1 y2 h 0..], B cols (N=32 queries) =
// [-x0 -x1 -x2 1 0..]; one MFMA = 1024 pair-t's. MFMA issued via inline asm
// with "v" constraints (gfx950 unified file: D in arch VGPRs, zacc pinned,
// no accvgpr_write/read traffic -- r12/r13 measured ~82 VALU inst/MFMA from
// the builtin's AGPR round-trip). CRITICAL (r14 failure): raw MFMA needs
// manual hazard wait-states before VALU may read D -- 3x s_nop 7 (24 cyc >=
// 18 required for 16-pass MFMA) embedded in the asm block; the nops are
// per-wave idle time hidden by the other ~7 resident waves per SIMD.
// B's k=8..15 half is zero, so A's high-half lanes read the same finite
// rows as the low half (x*0=0). Whole 32-ref tile = one argmin chunk:
// grouped min3 tree -> stuff 8-bit global chunk id into low mantissa ->
// fold into per-query best; cross-half shfl fold; plain keyed stores.
// f16 noise only affects WHICH chunk wins; finalize rescans in exact fp32.
__global__ __launch_bounds__(256) void chamfer_partial(
    const float* __restrict__ xyz1, const float* __restrict__ xyz2,
    float* __restrict__ part, float* __restrict__ out) {
    __shared__ half8 sA[SEGSZ];                 // packed ref frags, 8 KB

    const int tid = threadIdx.x;
    const int chq = blockIdx.x;                 // 0..15 (512-query chunks)
    const int seg = blockIdx.y;                 // 0..NSEG-1
    const int db = blockIdx.z;                  // 0..7
    const int dir = db >> 2, b = db & 3;

    // fold output zeroing into this kernel (finalize is a later dispatch)
    if (chq == 0 && seg == 0 && db == 0 && tid < 2) out[tid] = 0.0f;

    const float* Q = dir ? xyz2 : xyz1;
    const float* R = (dir ? xyz1 : xyz2) + ((size_t)b * NPTS + seg * SEGSZ) * 3;

    // pack refs: (y0, y1, y2, h, 0,0,0,0) as f16x8 (one A-frag row per ref)
    for (int k = tid; k < SEGSZ; k += 256) {
        float a = R[3 * k], c = R[3 * k + 1], e = R[3 * k + 2];
        float h = 0.5f * fmaf(a, a, fmaf(c, c, e * e));
        half8 v = {(_Float16)a, (_Float16)c, (_Float16)e, (_Float16)h,
                   (_Float16)0, (_Float16)0, (_Float16)0, (_Float16)0};
        sA[k] = v;
    }

    const int wave = tid >> 6, lane = tid & 63;
    const int n = lane & 31;
    const bool lohalf = lane < 32;              // k=0..7 carriers
    const int qbase = chq * QPB + wave * QPW;

    // B-frags: query col n; low half = [-x,-y,-z,1,0..], high half = zeros
    half8 bfrag[NQT];
    float best[NQT];
#pragma unroll
    for (int qt = 0; qt < NQT; ++qt) {
        half8 v = {(_Float16)0, (_Float16)0, (_Float16)0, (_Float16)0,
                   (_Float16)0, (_Float16)0, (_Float16)0, (_Float16)0};
        if (lohalf) {
            const size_t off = ((size_t)b * NPTS + qbase + qt * 32 + n) * 3;
            v[0] = (_Float16)(-Q[off]);
            v[1] = (_Float16)(-Q[off + 1]);
            v[2] = (_Float16)(-Q[off + 2]);
            v[3] = (_Float16)1.0f;
        }
        bfrag[qt] = v;
        best[qt] = BIGF;
    }
    __syncthreads();

    floatx16 zacc = {0.0f, 0.0f, 0.0f, 0.0f, 0.0f, 0.0f, 0.0f, 0.0f,
                     0.0f, 0.0f, 0.0f, 0.0f, 0.0f, 0.0f, 0.0f, 0.0f};
    const unsigned gc0 = seg * NTILE;           // global chunk id base (uniform)

    for (int rt = 0; rt < NTILE; ++rt) {
        // all 64 lanes read the same 32 rows (high half's k=8..15 B is zero,
        // so its A values are multiplied by 0 -- any finite data is fine)
        const half8 af = sA[rt * TILE + n];
        const unsigned gc = gc0 + rt;
#pragma unroll
        for (int qt = 0; qt < NQT; ++qt) {
            floatx16 d;
            asm("v_mfma_f32_32x32x16_f16 %0, %1, %2, %3\n\t"
                "s_nop 7\n\t"
                "s_nop 7\n\t"
                "s_nop 7"
                : "=&v"(d)
                : "v"(af), "v"(bfrag[qt]), "v"(zacc));
            // grouped-by-3 min tree -> v_min3_f32 x7 + final fmin
            float m0 = fminf(fminf(d[0], d[1]), d[2]);
            float m1 = fminf(fminf(d[3], d[4]), d[5]);
            float m2 = fminf(fminf(d[6], d[7]), d[8]);
            float m3 = fminf(fminf(d[9], d[10]), d[11]);
            float m4 = fminf(fminf(d[12], d[13]), d[14]);
            float n0 = fminf(fminf(m0, m1), m2);
            float n1 = fminf(fminf(m3, m4), d[15]);
            float mn = fminf(n0, n1);
            // (bits & CHMASK) | gc -> v_and_or_b32
            float key = __uint_as_float((__float_as_uint(mn) & CHMASK) | gc);
            best[qt] = fminf(best[qt], key);
        }
    }

    // cross-half fold (halves cover disjoint D rows) + plain keyed store
    const int qg = dir * (NB * NPTS) + b * NPTS + qbase;
#pragma unroll
    for (int qt = 0; qt < NQT; ++qt) {
        float v = best[qt];
        v = fminf(v, __shfl_xor(v, 32));
        if (lohalf) part[(size_t)seg * NQ_TOT + qg + qt * 32 + n] = v;
    }
}

// Phase 2: merge NSEG keyed segment minima (pure fminf, coalesced), decode
// winning 32-pt chunk, re-scan exactly via float4 loads, distance +
// normal-consistency, block-reduce, atomicAdd.
__global__ __launch_bounds__(256) void finalize_kernel(
    const float* __restrict__ xyz1, const float* __restrict__ xyz2,
    const float* __restrict__ nxyz1, const float* __restrict__ nxyz2,
    const float* __restrict__ part, float* __restrict__ out) {
    __shared__ float red[2][4];

    const int tid = threadIdx.x;
    const int q = blockIdx.x * 256 + tid;       // 0..65535
    const int dir = q >> 15;
    const int rem = q & 32767;
    const int b = rem >> 13;
    const int i = rem & 8191;

    float bt = part[q];
#pragma unroll
    for (int s = 1; s < NSEG; ++s) bt = fminf(bt, part[(size_t)s * NQ_TOT + q]);
    const int c = (int)(__float_as_uint(bt) & 0xFFu);  // global 32-pt chunk

    const float* Q   = dir ? xyz2 : xyz1;
    const float* Rf  = dir ? xyz1 : xyz2;
    const float* NQp = dir ? nxyz2 : nxyz1;
    const float* NRp = dir ? nxyz1 : nxyz2;

    const size_t qoff = ((size_t)b * NPTS + i) * 3;
    const float x0 = Q[qoff], x1 = Q[qoff + 1], x2 = Q[qoff + 2];
    const float n0 = -x0, n1 = -x1, n2 = -x2;

    // re-scan winning chunk (32 pts = 24 float4 loads; base 384B-aligned)
    const float4* Rs = (const float4*)(Rf + ((size_t)b * NPTS + c * CHSZ) * 3);
    float btr = BIGF;
    int bj = 0;
#pragma unroll
    for (int g = 0; g < 8; ++g) {               // 8 groups of 4 points
        const float4 f0 = Rs[3 * g];
        const float4 f1 = Rs[3 * g + 1];
        const float4 f2 = Rs[3 * g + 2];
        const float px[4] = {f0.x, f0.w, f1.z, f2.y};
        const float py[4] = {f0.y, f1.x, f1.w, f2.z};
        const float pz[4] = {f0.z, f1.y, f2.x, f2.w};
#pragma unroll
        for (int u = 0; u < 4; ++u) {
            float h = 0.5f * fmaf(px[u], px[u], fmaf(py[u], py[u], pz[u] * pz[u]));
            float t = fmaf(n0, px[u], fmaf(n1, py[u], fmaf(n2, pz[u], h)));
            int j = 4 * g + u;
            if (t < btr) { btr = t; bj = j; }   // strict <, ascending j: exact
        }
    }
    const int bi = c * CHSZ + bj;

    const size_t roff = ((size_t)b * NPTS + bi) * 3;
    const float y0 = Rf[roff], y1 = Rf[roff + 1], y2 = Rf[roff + 2];
    const float e0 = x0 - y0, e1 = x1 - y1, e2 = x2 - y2;
    float d = e0 * e0 + e1 * e1 + e2 * e2;      // exact squared distance

    const float a0 = NQp[qoff], a1 = NQp[qoff + 1], a2 = NQp[qoff + 2];
    const float c0 = NRp[roff], c1 = NRp[roff + 1], c2 = NRp[roff + 2];
    float na = sqrtf(a0 * a0 + a1 * a1 + a2 * a2);
    float nc = sqrtf(c0 * c0 + c1 * c1 + c2 * c2);
    float cs = (a0 * c0 + a1 * c1 + a2 * c2) /
               (fmaxf(na, CH_EPS) * fmaxf(nc, CH_EPS));
    float cn = 1.0f - fabsf(cs);

    for (int off = 32; off; off >>= 1) {
        d  += __shfl_down(d, off);
        cn += __shfl_down(cn, off);
    }
    const int lane = tid & 63, wv = tid >> 6;
    if (lane == 0) { red[0][wv] = d; red[1][wv] = cn; }
    __syncthreads();
    if (tid == 0) {
        float sd = red[0][0] + red[0][1] + red[0][2] + red[0][3];
        float sc = red[1][0] + red[1][1] + red[1][2] + red[1][3];
        const float inv = 1.0f / (float)(NB * NPTS);   // 1/32768
        atomicAdd(out + 0, sd * inv);
        atomicAdd(out + 1, sc * inv);
    }
}

extern "C" void kernel_launch(void* const* d_in, const int* in_sizes, int n_in,
                              void* d_out, int out_size, void* d_ws, size_t ws_size,
                              hipStream_t stream) {
    const float* xyz1  = (const float*)d_in[0];
    const float* xyz2  = (const float*)d_in[1];
    const float* nxyz1 = (const float*)d_in[2];
    const float* nxyz2 = (const float*)d_in[3];
    float* out = (float*)d_out;
    float* part = (float*)d_ws;                 // NSEG * 65536 * 4 B = 4 MB

    chamfer_partial<<<dim3(NPTS / QPB, NSEG, 2 * NB), dim3(256), 0, stream>>>(
        xyz1, xyz2, part, out);
    finalize_kernel<<<dim3(NQ_TOT / 256), dim3(256), 0, stream>>>(
        xyz1, xyz2, nxyz1, nxyz2, part, out);
}